// Round 1
// baseline (13243.144 us; speedup 1.0000x reference)
//
#include <hip/hip_runtime.h>
#include <cstdint>
#include <cstddef>

#define NN 100000
#define NE 800000
#define NG 64
#define NT 4
#define DD 150
#define HIDN 512
#define NPASS 5
#define NBINS (NN*NT)
#define LDA 151   // LDS A-tile row stride (floats): 4*LDA mod 32 = 28 -> 2-way (free)
#define WPS 152   // padded W row stride (floats): rows 16B-aligned for float4 loads

static __device__ __forceinline__ float sigmoidf_(float x){ return 1.f/(1.f+expf(-x)); }

// ---------------- setup: counting sort of edges by (dst,type) ----------------

__global__ void count_kernel(const int* __restrict__ dst, const int* __restrict__ typ,
                             unsigned* __restrict__ deg){
  int e = blockIdx.x*256 + threadIdx.x;
  if (e < NE) atomicAdd(&deg[dst[e]*NT + typ[e]], 1u);
}

__device__ unsigned block_excl_base(unsigned threadSum){
  const int tid = threadIdx.x;
  const int lane = tid & 63, wid = tid >> 6;
  unsigned s = threadSum;
  #pragma unroll
  for (int d = 1; d < 64; d <<= 1){ unsigned t = __shfl_up(s, d); if (lane >= d) s += t; }
  __shared__ unsigned wsum[4];
  if (lane == 63) wsum[wid] = s;
  __syncthreads();
  unsigned base = 0;
  for (int w = 0; w < wid; w++) base += wsum[w];
  return base + s - threadSum;
}

__global__ void scan_reduce(const unsigned* __restrict__ deg, unsigned* __restrict__ bsum){
  const int base = blockIdx.x*1024 + threadIdx.x*4;
  unsigned s = 0;
  #pragma unroll
  for (int i = 0; i < 4; i++){ const int idx = base+i; if (idx < NBINS) s += deg[idx]; }
  #pragma unroll
  for (int d = 1; d < 64; d <<= 1) s += __shfl_down(s, d);
  __shared__ unsigned ws4[4];
  const int lane = threadIdx.x & 63, wid = threadIdx.x >> 6;
  if (lane == 0) ws4[wid] = s;
  __syncthreads();
  if (threadIdx.x == 0) bsum[blockIdx.x] = ws4[0]+ws4[1]+ws4[2]+ws4[3];
}

__global__ void scan_block(unsigned* bsum, int n){
  const int tid = threadIdx.x;
  unsigned v[4]; unsigned s = 0;
  #pragma unroll
  for (int i = 0; i < 4; i++){ const int idx = tid*4+i; v[i] = (idx < n) ? bsum[idx] : 0u; s += v[i]; }
  unsigned run = block_excl_base(s);
  #pragma unroll
  for (int i = 0; i < 4; i++){ const int idx = tid*4+i; if (idx < n) bsum[idx] = run; run += v[i]; }
}

__global__ void scan_final(const unsigned* __restrict__ deg, const unsigned* __restrict__ bsum,
                           unsigned* __restrict__ off){
  const int tid = threadIdx.x;
  const int base0 = blockIdx.x*1024 + tid*4;
  unsigned v[4]; unsigned s = 0;
  #pragma unroll
  for (int i = 0; i < 4; i++){ const int idx = base0+i; v[i] = (idx < NBINS) ? deg[idx] : 0u; s += v[i]; }
  unsigned run = block_excl_base(s) + bsum[blockIdx.x];
  #pragma unroll
  for (int i = 0; i < 4; i++){ const int idx = base0+i; if (idx < NBINS) off[idx] = run; run += v[i]; }
  if (blockIdx.x == 0 && tid == 0) off[NBINS] = NE;
}

__global__ void scatter_sort(const int* __restrict__ src, const int* __restrict__ dst,
                             const int* __restrict__ typ, unsigned* __restrict__ cur,
                             int* __restrict__ srcSorted){
  int e = blockIdx.x*256 + threadIdx.x;
  if (e < NE){
    const int bin = dst[e]*NT + typ[e];
    const unsigned p = atomicAdd(&cur[bin], 1u);
    srcSorted[p] = src[e];
  }
}

__global__ void padW(const float* __restrict__ W, float* __restrict__ Wp, int rows){
  int idx = blockIdx.x*256 + threadIdx.x;
  if (idx < rows*DD){ const int n = idx/DD, k = idx - n*DD; Wp[n*WPS + k] = W[idx]; }
}

// inc[n,d] = sum_t deg[n,t] * b_e[t,d]   (per-edge Linear bias contribution)
__global__ void inc_init(const unsigned* __restrict__ deg, const float* __restrict__ b_e,
                         float* __restrict__ inc){
  const int idx = blockIdx.x*256 + threadIdx.x;
  if (idx < NN*DD){
    const int n = idx/DD, d = idx - n*DD;
    const unsigned* dg = &deg[n*NT];
    inc[idx] = (float)dg[0]*b_e[d] + (float)dg[1]*b_e[DD+d]
             + (float)dg[2]*b_e[2*DD+d] + (float)dg[3]*b_e[3*DD+d];
  }
}

// ---------------- the GEMM: C[row, col0+n] (+)= sum_k A[row,k]*W[n,k] ----------------
// AGG mode: A-tile is built in LDS by CSR segment-sum gather of h rows (message phase).
// Plain mode: A-tile loaded from global (GRU gi/gh), bias added, direct store.
template<bool AGG, bool ACC>
__global__ __launch_bounds__(256, 4) void gemm_k150(
    const float* __restrict__ A, const float* __restrict__ W,
    float* __restrict__ C, const float* __restrict__ bias,
    const float* __restrict__ hsrc, const int* __restrict__ srcSorted,
    const unsigned* __restrict__ off, int typeT, int M, int ldc)
{
  __shared__ float As[64*LDA];
  const int tid = threadIdx.x;
  const int rowTile = blockIdx.x * 64;
  const float* __restrict__ Wb = W + (size_t)blockIdx.y * (DD*WPS);
  const int col0 = blockIdx.y * DD;

  if (AGG) {
    const int lane = tid & 63, sub = tid >> 6;
    for (int i = 0; i < 16; i++) {
      const int m = sub*16 + i;
      const int node = rowTile + m;
      float a0 = 0.f, a1 = 0.f, a2 = 0.f;
      if (node < NN) {
        const int bin = node*NT + typeT;
        const unsigned lo = off[bin], hi = off[bin+1];
        for (unsigned e = lo; e < hi; e++) {
          const int s = srcSorted[e];
          const float* hp = hsrc + (size_t)s*DD;
          a0 += hp[lane];
          if (lane < DD-64)  a1 += hp[lane+64];
          if (lane < DD-128) a2 += hp[lane+128];
        }
      }
      As[m*LDA + lane] = a0;
      if (lane < DD-64)  As[m*LDA + lane + 64]  = a1;
      if (lane < DD-128) As[m*LDA + lane + 128] = a2;
    }
  } else {
    for (int idx = tid; idx < 64*DD; idx += 256) {
      const int m = idx / DD, k = idx - m*DD;
      const int r = rowTile + m;
      As[m*LDA + k] = (r < M) ? A[(size_t)r*DD + k] : 0.f;
    }
  }
  __syncthreads();

  const int tm = tid & 15, tn = tid >> 4;   // rows 4*tm..4*tm+3, cols 16*j+tn
  float acc[4][10];
  #pragma unroll
  for (int r = 0; r < 4; r++)
    #pragma unroll
    for (int j = 0; j < 10; j++) acc[r][j] = 0.f;

  const float* Ab = &As[(4*tm)*LDA];

  #pragma unroll 2
  for (int k4 = 0; k4 < 37; k4++) {
    const int k = 4*k4;
    float a[4][4];
    #pragma unroll
    for (int r = 0; r < 4; r++){
      a[r][0] = Ab[r*LDA+k];   a[r][1] = Ab[r*LDA+k+1];
      a[r][2] = Ab[r*LDA+k+2]; a[r][3] = Ab[r*LDA+k+3];
    }
    #pragma unroll
    for (int j = 0; j < 10; j++){
      const int n = 16*j + tn;
      if (n < DD) {
        const float4 w = *(const float4*)(Wb + (size_t)n*WPS + k);
        #pragma unroll
        for (int r = 0; r < 4; r++)
          acc[r][j] = fmaf(a[r][0], w.x, fmaf(a[r][1], w.y,
                      fmaf(a[r][2], w.z, fmaf(a[r][3], w.w, acc[r][j]))));
      }
    }
  }
  { // k tail: 148, 149
    float a[4][2];
    #pragma unroll
    for (int r = 0; r < 4; r++){ a[r][0] = Ab[r*LDA+148]; a[r][1] = Ab[r*LDA+149]; }
    #pragma unroll
    for (int j = 0; j < 10; j++){
      const int n = 16*j + tn;
      if (n < DD) {
        const float2 w = *(const float2*)(Wb + (size_t)n*WPS + 148);
        #pragma unroll
        for (int r = 0; r < 4; r++)
          acc[r][j] = fmaf(a[r][0], w.x, fmaf(a[r][1], w.y, acc[r][j]));
      }
    }
  }

  #pragma unroll
  for (int r = 0; r < 4; r++){
    const int row = rowTile + 4*tm + r;
    if (row < M) {
      #pragma unroll
      for (int j = 0; j < 10; j++){
        const int n = 16*j + tn;
        if (n < DD) {
          const size_t ci = (size_t)row*ldc + col0 + n;
          if (ACC) C[ci] += acc[r][j];
          else     C[ci] = acc[r][j] + bias[col0+n];
        }
      }
    }
  }
}

// ---------------- GRU elementwise (gate order r,z,n; biases already in GI/GH) ----------------
__global__ void gru_kernel(const float* __restrict__ GI, const float* __restrict__ GH,
                           float* __restrict__ h, int c0, int m){
  const int idx = blockIdx.x*256 + threadIdx.x;
  if (idx >= m*DD) return;
  const int i = idx / DD, d = idx - i*DD;
  const float* gi = GI + (size_t)i*3*DD;
  const float* gh = GH + (size_t)i*3*DD;
  const float r = sigmoidf_(gi[d]      + gh[d]);
  const float z = sigmoidf_(gi[DD+d]   + gh[DD+d]);
  const float n = tanhf(gi[2*DD+d] + r*gh[2*DD+d]);
  const size_t hidx = (size_t)(c0+i)*DD + d;
  const float hv = h[hidx];
  h[hidx] = (1.f - z)*n + z*hv;
}

// ---------------- readout: segment-sum per graph (sorted ids), log/nan/relu, concat ----------------
__global__ void readout(const float* __restrict__ h, const int* __restrict__ gids,
                        const float* __restrict__ pclass, float* __restrict__ xbuf){
  const int b = blockIdx.x, tid = threadIdx.x;
  __shared__ int sb[2];
  if (tid < 2) {
    const int target = b + tid;
    int lo = 0, hi = NN;
    while (lo < hi){ const int mid = (lo+hi) >> 1; if (gids[mid] < target) lo = mid+1; else hi = mid; }
    sb[tid] = lo;
  }
  __syncthreads();
  const int lo = sb[0], hi = sb[1];
  if (tid < DD) {
    float acc = 0.f;
    for (int n = lo; n < hi; n++) acc += h[(size_t)n*DD + tid];
    float l = logf(acc);            // log(neg)=NaN, log(0)=-inf
    if (isnan(l)) l = 0.f;          // nan -> 0
    l = fmaxf(l, 0.f);              // relu (also kills -inf)
    xbuf[b*(DD+1)+tid] = l;
  }
  if (tid == DD) xbuf[b*(DD+1)+DD] = pclass[b];
}

__global__ void fc1_kernel(const float* __restrict__ xbuf, const float* __restrict__ w,
                           const float* __restrict__ b, float* __restrict__ hid){
  const int g = blockIdx.x, tid = threadIdx.x;   // 512 threads
  __shared__ float xs[DD+1];
  if (tid < DD+1) xs[tid] = xbuf[g*(DD+1)+tid];
  __syncthreads();
  float acc = b[tid];
  for (int k = 0; k < DD+1; k++) acc = fmaf(xs[k], w[k*HIDN + tid], acc);
  hid[g*HIDN + tid] = (acc > 0.f) ? acc : 0.01f*acc;   // leaky_relu(0.01)
}

__global__ void fc2_kernel(const float* __restrict__ hid, const float* __restrict__ w,
                           const float* __restrict__ b, float* __restrict__ out){
  const int g = blockIdx.x, tid = threadIdx.x;   // 64 threads
  __shared__ float hs[HIDN];
  for (int i = tid; i < HIDN; i += 64) hs[i] = hid[g*HIDN + i];
  __syncthreads();
  if (tid < 10){
    float acc = b[tid];
    for (int k = 0; k < HIDN; k++) acc = fmaf(hs[k], w[k*10 + tid], acc);
    out[g*10 + tid] = acc;
  }
}

// ---------------- host orchestration ----------------
extern "C" void kernel_launch(void* const* d_in, const int* in_sizes, int n_in,
                              void* d_out, int out_size, void* d_ws, size_t ws_size,
                              hipStream_t stream)
{
  (void)in_sizes; (void)n_in; (void)out_size;
  const float* nodes  = (const float*)d_in[0];
  const float* pclass = (const float*)d_in[1];
  const int*   esrc   = (const int*)d_in[2];
  const int*   edst   = (const int*)d_in[3];
  const int*   etyp   = (const int*)d_in[4];
  const int*   gids   = (const int*)d_in[5];
  const float* W_e    = (const float*)d_in[6];
  const float* b_e    = (const float*)d_in[7];
  const float* w_ih   = (const float*)d_in[8];
  const float* w_hh   = (const float*)d_in[9];
  const float* b_ih   = (const float*)d_in[10];
  const float* b_hh   = (const float*)d_in[11];
  const float* fc1w   = (const float*)d_in[12];
  const float* fc1b   = (const float*)d_in[13];
  const float* fc2w   = (const float*)d_in[14];
  const float* fc2b   = (const float*)d_in[15];
  float* out = (float*)d_out;

  char* p = (char*)d_ws;
  auto alloc = [&](size_t bytes)->char* {
    char* r = p; p += ((bytes + 255) & ~(size_t)255); return r;
  };
  float*    h    = (float*)alloc((size_t)NN*DD*4);          // 60 MB
  float*    inc  = (float*)alloc((size_t)NN*DD*4);          // 60 MB
  unsigned* deg  = (unsigned*)alloc((size_t)NBINS*4);
  unsigned* off  = (unsigned*)alloc((size_t)(NBINS+1)*4);
  unsigned* cur  = (unsigned*)alloc((size_t)NBINS*4);
  unsigned* bsum = (unsigned*)alloc(4096);
  int*      srcS = (int*)alloc((size_t)NE*4);
  float*    WpE  = (float*)alloc((size_t)NT*DD*WPS*4);
  float*    WpI  = (float*)alloc((size_t)3*DD*WPS*4);
  float*    WpH  = (float*)alloc((size_t)3*DD*WPS*4);
  float*    xbuf = (float*)alloc((size_t)NG*(DD+1)*4);
  float*    hidb = (float*)alloc((size_t)NG*HIDN*4);

  const size_t used = (size_t)(p - (char*)d_ws);
  const size_t remain = (ws_size > used) ? (ws_size - used) : 0;
  long long cm = (long long)(remain / (2ull*3*DD*4));
  if (cm > NN) cm = NN;
  cm &= ~63LL;
  if (cm < 64) cm = 64;
  const int chunkM = (int)cm;
  float* GI = (float*)p;
  float* GH = GI + (size_t)chunkM*3*DD;

  // --- per-launch setup (edge CSR sort + padded weights + h init) ---
  hipMemsetAsync(deg, 0, (size_t)NBINS*4, stream);
  count_kernel<<<(NE+255)/256, 256, 0, stream>>>(edst, etyp, deg);
  const int SCB = (NBINS + 1023)/1024;   // 391
  scan_reduce<<<SCB, 256, 0, stream>>>(deg, bsum);
  scan_block<<<1, 256, 0, stream>>>(bsum, SCB);
  scan_final<<<SCB, 256, 0, stream>>>(deg, bsum, off);
  hipMemcpyAsync(cur, off, (size_t)NBINS*4, hipMemcpyDeviceToDevice, stream);
  scatter_sort<<<(NE+255)/256, 256, 0, stream>>>(esrc, edst, etyp, cur, srcS);
  padW<<<(NT*DD*DD+255)/256, 256, 0, stream>>>(W_e, WpE, NT*DD);
  padW<<<(3*DD*DD+255)/256, 256, 0, stream>>>(w_ih, WpI, 3*DD);
  padW<<<(3*DD*DD+255)/256, 256, 0, stream>>>(w_hh, WpH, 3*DD);
  hipMemcpyAsync(h, nodes, (size_t)NN*DD*4, hipMemcpyDeviceToDevice, stream);

  const int grows = (NN + 63)/64;
  for (int pass = 0; pass < NPASS; pass++) {
    inc_init<<<(NN*DD+255)/256, 256, 0, stream>>>(deg, b_e, inc);
    for (int t = 0; t < NT; t++) {
      gemm_k150<true,true><<<dim3(grows,1), 256, 0, stream>>>(
        nullptr, WpE + (size_t)t*DD*WPS, inc, nullptr, h, srcS, off, t, NN, DD);
    }
    for (int c = 0; c < NN; c += chunkM) {
      const int m = (NN - c < chunkM) ? (NN - c) : chunkM;
      const int gb = (m + 63)/64;
      gemm_k150<false,false><<<dim3(gb,3), 256, 0, stream>>>(
        inc + (size_t)c*DD, WpI, GI, b_ih, nullptr, nullptr, nullptr, 0, m, 3*DD);
      gemm_k150<false,false><<<dim3(gb,3), 256, 0, stream>>>(
        h + (size_t)c*DD, WpH, GH, b_hh, nullptr, nullptr, nullptr, 0, m, 3*DD);
      gru_kernel<<<(int)(((size_t)m*DD + 255)/256), 256, 0, stream>>>(GI, GH, h, c, m);
    }
  }

  readout<<<NG, 256, 0, stream>>>(h, gids, pclass, xbuf);
  fc1_kernel<<<NG, HIDN, 0, stream>>>(xbuf, fc1w, fc1b, hidb);
  fc2_kernel<<<NG, 64, 0, stream>>>(hidb, fc2w, fc2b, out);
}